// Round 2
// baseline (17.321 us; speedup 1.0000x reference)
//
#include <hip/hip_runtime.h>
#include <math.h>

// DescriptorMatcher: b=1, c=64, N=1024.
// out  [N*N, 2] : out[i,j,o] = sum_c v1[i,c]*v2[j,c]*W[o,c] + bias[o]
// onorm[N, N]   : || v1/(eps+|v1|) - v2/(eps+|v2|) ||
//               = sqrt(s1[i] + s2[j] - 2*dot(i,j)*r1[i]*r2[j])
// Shared-product inner loop: p = a*b; accd += p; acc0 += p*w0c; acc1 += p*w1c
// with w0c/w1c as uniform scalar loads (SGPR) -> only 32 B/lane/c of LDS reads.
// 32x32 tile, 64-thread (1-wave) blocks, 1024 blocks = 4 blocks/CU resident.

#define CDIM 64
#define TI 32
#define TJ 32
#define EPSN 1e-6f

typedef float f4 __attribute__((ext_vector_type(4)));

__global__ __launch_bounds__(64)
void descmatch_kernel(const float* __restrict__ g1,
                      const float* __restrict__ g2,
                      const float* __restrict__ W,
                      const float* __restrict__ bias,
                      float* __restrict__ out,
                      float* __restrict__ onorm,
                      int N) {
    __shared__ float v1s[CDIM][TI];   // [c][i]
    __shared__ float v2s[CDIM][TJ];   // [c][j]
    __shared__ float s1t[TI], r1t[TI], s2t[TJ], r2t[TJ];

    const int t  = threadIdx.x;        // 0..63
    const int i0 = blockIdx.y * TI;
    const int j0 = blockIdx.x * TJ;

    // ---- stage tiles (f4 global loads -> f4 LDS writes, fully coalesced)
    #pragma unroll
    for (int p = 0; p < 8; ++p) {
        int idx = p * 64 + t;          // 0..511 f4-chunks per array
        int c = idx >> 3;              // 64 rows
        int j = (idx & 7) * 4;         // 8 f4 per row
        *(f4*)&v1s[c][j] = *(const f4*)&g1[c * N + i0 + j];
        *(f4*)&v2s[c][j] = *(const f4*)&g2[c * N + j0 + j];
    }
    __syncthreads();

    // ---- per-row norm scalars: thread t<32 -> v1 row t, t>=32 -> v2 row t-32
    {
        int r = t & 31;
        const float* col = (t < 32) ? &v1s[0][r] : &v2s[0][r]; // stride TI==TJ
        float ss = 0.f;
        #pragma unroll
        for (int c = 0; c < CDIM; ++c) { float x = col[c * TI]; ss += x * x; }
        float inv = 1.0f / (EPSN + sqrtf(ss));
        if (t < 32) { s1t[r] = ss * inv * inv; r1t[r] = inv; }
        else        { s2t[r] = ss * inv * inv; r2t[r] = inv; }
    }
    __syncthreads();

    // ---- main: 4x4 pairs per thread
    const int tx = t & 7;              // j group (8*4 = 32)
    const int ty = t >> 3;             // i group (8*4 = 32)
    const int jb = tx * 4;
    const int ib = ty * 4;

    const float b0 = bias[0];
    const float b1 = bias[1];

    float acc0[4][4], acc1[4][4], accd[4][4];
    #pragma unroll
    for (int ii = 0; ii < 4; ++ii)
        #pragma unroll
        for (int jj = 0; jj < 4; ++jj) {
            acc0[ii][jj] = b0; acc1[ii][jj] = b1; accd[ii][jj] = 0.f;
        }

    #pragma unroll 8
    for (int c = 0; c < CDIM; ++c) {
        f4 a = *(const f4*)&v1s[c][ib];
        f4 b = *(const f4*)&v2s[c][jb];
        const float w0c = W[c];            // uniform -> s_load
        const float w1c = W[CDIM + c];     // uniform -> s_load
        #pragma unroll
        for (int ii = 0; ii < 4; ++ii)
            #pragma unroll
            for (int jj = 0; jj < 4; ++jj) {
                float p = a[ii] * b[jj];
                accd[ii][jj] += p;
                acc0[ii][jj] = fmaf(p, w0c, acc0[ii][jj]);
                acc1[ii][jj] = fmaf(p, w1c, acc1[ii][jj]);
            }
    }

    // ---- epilogue
    f4 s2v = *(const f4*)&s2t[jb];
    f4 r2v = *(const f4*)&r2t[jb];

    #pragma unroll
    for (int ii = 0; ii < 4; ++ii) {
        const int i = i0 + ib + ii;
        const float s1  = s1t[ib + ii];
        const float r1x = -2.0f * r1t[ib + ii];

        f4 o01, o23, dn;
        o01[0] = acc0[ii][0]; o01[1] = acc1[ii][0];
        o01[2] = acc0[ii][1]; o01[3] = acc1[ii][1];
        o23[0] = acc0[ii][2]; o23[1] = acc1[ii][2];
        o23[2] = acc0[ii][3]; o23[3] = acc1[ii][3];

        #pragma unroll
        for (int jj = 0; jj < 4; ++jj) {
            float d2 = fmaf(accd[ii][jj] * r1x, r2v[jj], s1 + s2v[jj]);
            dn[jj] = sqrtf(fmaxf(d2, 0.0f));
        }

        const size_t base = (size_t)i * N + (j0 + jb);
        *(f4*)&out[base * 2]     = o01;
        *(f4*)&out[base * 2 + 4] = o23;
        *(f4*)&onorm[base]       = dn;
    }
}

extern "C" void kernel_launch(void* const* d_in, const int* in_sizes, int n_in,
                              void* d_out, int out_size, void* d_ws, size_t ws_size,
                              hipStream_t stream) {
    const float* g1   = (const float*)d_in[0];
    const float* g2   = (const float*)d_in[1];
    const float* W    = (const float*)d_in[2];
    const float* bias = (const float*)d_in[3];

    const int N = in_sizes[0] / CDIM;          // 1024
    float* out   = (float*)d_out;              // [N*N, 2]
    float* onorm = out + (size_t)2 * N * N;    // [N, N]

    dim3 grid(N / TJ, N / TI);                 // 32 x 32 = 1024 blocks
    descmatch_kernel<<<grid, 64, 0, stream>>>(g1, g2, W, bias, out, onorm, N);
}